// Round 10
// baseline (924.171 us; speedup 1.0000x reference)
//
#include <hip/hip_runtime.h>

#define CRANGE 3.75f       // 15.0 / 4 layers

typedef _Float16 half_t;
typedef __attribute__((ext_vector_type(8))) _Float16 half8;
typedef __attribute__((ext_vector_type(4))) _Float16 half4;
typedef __attribute__((ext_vector_type(4))) float f32x4;

__device__ __forceinline__ float frcp(float x) { return __builtin_amdgcn_rcpf(x); }
__device__ __forceinline__ float fexpn(float x) { return __expf(fminf(x, 20.f)); }
__device__ __forceinline__ float fsilu(float x) { return x * frcp(1.f + fexpn(-x)); }

__device__ __forceinline__ void inv4(float d0, float d1, float d2, float d3, float* o) {
    float p01 = d0 * d1, p23 = d2 * d3;
    float r = frcp(p01 * p23);
    float t01 = p23 * r, t23 = p01 * r;
    o[0] = d1 * t01; o[1] = d0 * t01; o[2] = d3 * t23; o[3] = d2 * t23;
}
__device__ __forceinline__ void silu4(const float* x, float* o) {
    float d0 = 1.f + fexpn(-x[0]), d1 = 1.f + fexpn(-x[1]);
    float d2 = 1.f + fexpn(-x[2]), d3 = 1.f + fexpn(-x[3]);
    float iv[4]; inv4(d0, d1, d2, d3, iv);
    o[0] = x[0] * iv[0]; o[1] = x[1] * iv[1]; o[2] = x[2] * iv[2]; o[3] = x[3] * iv[3];
}

struct MP {
    const float* x0; float* cA; float* cB;
    float* Hr; float* Hc; float* h; float* agg;
    const float* ew1; const float* eb1; const float* eb2; const float* cb1;
    const float* attw; const float* attb; const float* cw2; const float* nm;
    const half_t* wf; const float* trT;
    const float* nb1; const float* nb2;
    float* out; int* bar; int nblk;
};

// device-scope grid barrier; one fresh counter per use (no sense reversal).
// Requires all blocks co-resident (grid sized from occupancy API).
__device__ __forceinline__ void gridbar(int* cnt, int nblk) {
    __syncthreads();
    if (threadIdx.x == 0) {
        __threadfence();
        int arrived = __hip_atomic_fetch_add(cnt, 1, __ATOMIC_ACQ_REL, __HIP_MEMORY_SCOPE_AGENT) + 1;
        if (arrived < nblk) {
            while (__hip_atomic_load(cnt, __ATOMIC_ACQUIRE, __HIP_MEMORY_SCOPE_AGENT) < nblk)
                __builtin_amdgcn_s_sleep(2);
        }
    }
    __syncthreads();
}

// ---------------- K_prepinit: wf frags + trT transposes + node init + barrier zero ----------------
__global__ __launch_bounds__(256) void k_prepinit(
    const float* __restrict__ ew2, const float* __restrict__ cw1,
    const float* __restrict__ nw1, const float* __restrict__ nw2,
    const float* __restrict__ ew1,
    half_t* __restrict__ wf, float* __restrict__ trT, int* __restrict__ bar,
    const float* __restrict__ t, const float* __restrict__ x,
    const float* __restrict__ at, const float* __restrict__ aa,
    const float* __restrict__ ap, const float* __restrict__ nm,
    const float* __restrict__ embw, const float* __restrict__ embb,
    const float* __restrict__ eb1_0,
    float* __restrict__ h, float* __restrict__ Hr, float* __restrict__ Hc,
    float* __restrict__ x0, float* __restrict__ cA)
{
    if (blockIdx.x == 0 && threadIdx.x < 16) bar[threadIdx.x] = 0;
    if (blockIdx.x < 336) {
        int idx = blockIdx.x * 256 + threadIdx.x;
        if (idx < 4096) {
            int lane = idx & 63;
            int g = (idx >> 6) & 7;
            int mat = (idx >> 9) & 1;
            int l = idx >> 10;
            int mt = g >> 1, kc = g & 1;
            int c = lane & 15, qq = lane >> 4;
            const float* W = (mat ? cw1 : ew2) + l * 4096;
            int row = 16 * mt + c;
            int k0 = 32 * kc + 8 * qq;
            half8 pk;
#pragma unroll
            for (int j = 0; j < 8; ++j) pk[j] = (half_t)W[row * 64 + k0 + j];
            ((half8*)wf)[idx] = pk;
        }
        int tid2 = idx - 4096;
        if (tid2 >= 0 && tid2 < 81920) {
            int l = tid2 / 20480, r = tid2 % 20480;
            float v;
            if (r < 8192)       { int k = r >> 6,        c = r & 63; v = nw1[l * 8192 + c * 128 + k]; }
            else if (r < 12288) { int r2 = r - 8192,  k = r2 >> 6, c = r2 & 63; v = nw2[l * 4096 + c * 64 + k]; }
            else if (r < 16384) { int r2 = r - 12288, k = r2 >> 6, c = r2 & 63; v = ew1[l * 8320 + c * 130 + k]; }
            else                { int r2 = r - 16384, k = r2 >> 6, c = r2 & 63; v = ew1[l * 8320 + c * 130 + 64 + k]; }
            trT[l * 20480 + r] = v;
        }
        return;
    }
    // ---- init: 4 nodes per block ----
    __shared__ float sh[4][64];
    int g = threadIdx.x >> 6, c = threadIdx.x & 63;
    int n = (blockIdx.x - 336) * 4 + g;
    float m = nm[n]; int b = n >> 8;
    float i0 = at[n] * m, i1 = aa[n] * m, i2 = ap[n] * m, i3 = t[b] * m;
    float4 w = ((const float4*)embw)[c];
    float hv = w.x * i0 + w.y * i1 + w.z * i2 + w.w * i3 + embb[c];
    sh[g][c] = hv; h[n * 64 + c] = hv;
    if (c < 3) { float v = x[n * 3 + c] * m; x0[n * 3 + c] = v; cA[n * 3 + c] = v; }
    __syncthreads();
    float a = eb1_0[c], bb = 0.f;
    const float* wa = ew1 + c * 130;
#pragma unroll
    for (int k = 0; k < 64; ++k) {
        float hk = sh[g][k];
        a  += wa[k] * hk;
        bb += wa[64 + k] * hk;
    }
    Hr[n * 64 + c] = a;
    Hc[n * 64 + c] = bb;
}

// ---------------- K_mega: persistent — 4x(edge phase, tail phase) + final, grid barriers ----------------
__global__ __launch_bounds__(256, 4) void k_mega(MP p)
{
    __shared__ __align__(16) half_t sV[4][4096];
    __shared__ __align__(16) float sGeo[4][64][4];
    __shared__ float sHr[64], sWr[64], sWe[64], sB2[64], sBc1[64], sAttw[64], sWc2[64];
    __shared__ float sAgg[64];
    __shared__ float sCoord[3];

    const int t = threadIdx.x, wv = t >> 6, e = t & 63;
    const int q = e >> 4, c = e & 15;

    for (int l = 0; l < 4; ++l) {
        const float* ew1l = p.ew1 + l * 8320;
        const float* eb2l = p.eb2 + l * 64;
        const float* cb1l = p.cb1 + l * 64;
        const float* awl  = p.attw + l * 64;
        const float  attb0 = p.attb[l];
        const float* cw2l = p.cw2 + l * 64;
        const half_t* wf2 = p.wf + l * 8192;
        const half_t* wf1 = p.wf + l * 8192 + 4096;
        const float* coordIn  = (l & 1) ? p.cB : p.cA;
        float*       coordOut = (l & 1) ? p.cA : p.cB;

        // ================= edge phase: grid-stride over destination nodes =================
        for (int i = blockIdx.x; i < 2048; i += gridDim.x) {
            const int b = i >> 8, ir = i & 255;
            const int col = (b << 8) + t;

            if (t < 64) {
                sHr[t] = p.Hr[i * 64 + t];
                sWr[t] = ew1l[t * 130 + 128];
                sWe[t] = ew1l[t * 130 + 129];
                sB2[t] = eb2l[t]; sBc1[t] = cb1l[t]; sAttw[t] = awl[t]; sWc2[t] = cw2l[t];
                sAgg[t] = 0.f;
            }
            if (t == 64) { sCoord[0] = 0.f; sCoord[1] = 0.f; sCoord[2] = 0.f; }
            float nmi = p.nm[i];

            float dx = coordIn[i*3+0] - coordIn[col*3+0];
            float dy = coordIn[i*3+1] - coordIn[col*3+1];
            float dz = coordIn[i*3+2] - coordIn[col*3+2];
            float radial = dx*dx + dy*dy + dz*dz;
            float inv = frcp(__builtin_amdgcn_sqrtf(radial + 1e-8f) + 1.f);
            float ex = p.x0[i*3+0] - p.x0[col*3+0];
            float ey = p.x0[i*3+1] - p.x0[col*3+1];
            float ez = p.x0[i*3+2] - p.x0[col*3+2];
            float e0 = ex*ex + ey*ey + ez*ez;
            float em = nmi * p.nm[col] * ((t == ir) ? 0.f : 1.f);

            __syncthreads();

            {
                float4 g4 = make_float4(dx*inv, dy*inv, dz*inv, em);
                *(float4*)&sGeo[wv][e][0] = g4;
            }

            half_t* mybuf = (half_t*)sV[wv];
            const float4* hcv = (const float4*)(p.Hc + col * 64);
#pragma unroll
            for (int s = 0; s < 8; ++s) {
                float4 ha = hcv[2*s], hb = hcv[2*s+1];
                float z[8], so[8];
                z[0]=ha.x; z[1]=ha.y; z[2]=ha.z; z[3]=ha.w;
                z[4]=hb.x; z[5]=hb.y; z[6]=hb.z; z[7]=hb.w;
#pragma unroll
                for (int u = 0; u < 8; ++u) {
                    int k = 8*s + u;
                    z[u] = sHr[k] + z[u] + radial * sWr[k] + e0 * sWe[k];
                }
                silu4(z, so); silu4(z + 4, so + 4);
                half8 pk;
#pragma unroll
                for (int u = 0; u < 8; ++u) pk[u] = (half_t)so[u];
                int f = q * 2 + (s >> 2);
                *(half8*)&mybuf[f * 512 + ((s & 3) * 16 + c) * 8] = pk;
            }

            const half8* bv = (const half8*)mybuf;
            f32x4 acc[4][4];
#pragma unroll
            for (int mt = 0; mt < 4; ++mt) {
                int row0 = 16*mt + 4*q;
#pragma unroll
                for (int nt = 0; nt < 4; ++nt)
#pragma unroll
                    for (int r = 0; r < 4; ++r) acc[mt][nt][r] = sB2[row0 + r];
            }
            {
                const half8* a2v = (const half8*)wf2;
                half8 a2[8];
#pragma unroll
                for (int g = 0; g < 8; ++g) a2[g] = a2v[g * 64 + e];
#pragma unroll
                for (int nt = 0; nt < 4; ++nt) {
                    half8 b0 = bv[(nt*2+0)*64 + e];
                    half8 b1 = bv[(nt*2+1)*64 + e];
#pragma unroll
                    for (int mt = 0; mt < 4; ++mt) {
                        acc[mt][nt] = __builtin_amdgcn_mfma_f32_16x16x32_f16(a2[mt*2+0], b0, acc[mt][nt], 0, 0, 0);
                        acc[mt][nt] = __builtin_amdgcn_mfma_f32_16x16x32_f16(a2[mt*2+1], b1, acc[mt][nt], 0, 0, 0);
                    }
                }
            }

            float attp[4] = {0.f, 0.f, 0.f, 0.f};
#pragma unroll
            for (int mt = 0; mt < 4; ++mt) {
                int row0 = 16*mt + 4*q;
#pragma unroll
                for (int nt = 0; nt < 4; ++nt) {
                    float z[4], so[4];
#pragma unroll
                    for (int r = 0; r < 4; ++r) z[r] = acc[mt][nt][r];
                    silu4(z, so);
#pragma unroll
                    for (int r = 0; r < 4; ++r) {
                        acc[mt][nt][r] = so[r];
                        attp[nt] += so[r] * sAttw[row0 + r];
                    }
                }
            }
#pragma unroll
            for (int nt = 0; nt < 4; ++nt) {
                float v = attp[nt];
                v += __shfl_xor(v, 16);
                v += __shfl_xor(v, 32);
                attp[nt] = v;
            }
            float scale[4];
            {
                float d0 = 1.f + fexpn(-(attp[0] + attb0));
                float d1 = 1.f + fexpn(-(attp[1] + attb0));
                float d2 = 1.f + fexpn(-(attp[2] + attb0));
                float d3 = 1.f + fexpn(-(attp[3] + attb0));
                float iv[4]; inv4(d0, d1, d2, d3, iv);
#pragma unroll
                for (int nt = 0; nt < 4; ++nt) scale[nt] = iv[nt] * sGeo[wv][16*nt + c][3];
            }

            float aggp[4][4];
#pragma unroll
            for (int mt = 0; mt < 4; ++mt)
#pragma unroll
                for (int r = 0; r < 4; ++r) aggp[mt][r] = 0.f;
#pragma unroll
            for (int mt = 0; mt < 4; ++mt) {
                int kbase = 16*mt + 4*q;
                int fof = ((kbase >> 5) * 512) + (((kbase >> 3) & 3) * 128) + (kbase & 7);
#pragma unroll
                for (int nt = 0; nt < 4; ++nt) {
                    half4 pk;
#pragma unroll
                    for (int r = 0; r < 4; ++r) {
                        float v = acc[mt][nt][r] * scale[nt];
                        aggp[mt][r] += v;
                        pk[r] = (half_t)v;
                    }
                    *(half4*)&mybuf[nt*1024 + fof + c*8] = pk;
                }
            }

            half8 a1[8];
            {
                const half8* a1v = (const half8*)wf1;
#pragma unroll
                for (int g = 0; g < 8; ++g) a1[g] = a1v[g * 64 + e];
            }

#pragma unroll
            for (int mt = 0; mt < 4; ++mt)
#pragma unroll
                for (int r = 0; r < 4; ++r) {
                    float v = aggp[mt][r];
                    v += __shfl_xor(v, 1); v += __shfl_xor(v, 2);
                    v += __shfl_xor(v, 4); v += __shfl_xor(v, 8);
                    if (c == 0) atomicAdd(&sAgg[16*mt + 4*q + r], v);
                }

            f32x4 acc2[4][4];
#pragma unroll
            for (int mt = 0; mt < 4; ++mt) {
                int row0 = 16*mt + 4*q;
#pragma unroll
                for (int nt = 0; nt < 4; ++nt)
#pragma unroll
                    for (int r = 0; r < 4; ++r) acc2[mt][nt][r] = sBc1[row0 + r];
            }
#pragma unroll
            for (int nt = 0; nt < 4; ++nt) {
                half8 b0 = bv[(nt*2+0)*64 + e];
                half8 b1 = bv[(nt*2+1)*64 + e];
#pragma unroll
                for (int mt = 0; mt < 4; ++mt) {
                    acc2[mt][nt] = __builtin_amdgcn_mfma_f32_16x16x32_f16(a1[mt*2+0], b0, acc2[mt][nt], 0, 0, 0);
                    acc2[mt][nt] = __builtin_amdgcn_mfma_f32_16x16x32_f16(a1[mt*2+1], b1, acc2[mt][nt], 0, 0, 0);
                }
            }

            float php[4] = {0.f, 0.f, 0.f, 0.f};
#pragma unroll
            for (int mt = 0; mt < 4; ++mt) {
                int row0 = 16*mt + 4*q;
#pragma unroll
                for (int nt = 0; nt < 4; ++nt) {
                    float z[4], so[4];
#pragma unroll
                    for (int r = 0; r < 4; ++r) z[r] = acc2[mt][nt][r];
                    silu4(z, so);
#pragma unroll
                    for (int r = 0; r < 4; ++r) php[nt] += so[r] * sWc2[row0 + r];
                }
            }
#pragma unroll
            for (int nt = 0; nt < 4; ++nt) {
                float v = php[nt];
                v += __shfl_xor(v, 16);
                v += __shfl_xor(v, 32);
                php[nt] = v;
            }
            float tnh[4];
            {
                float d0 = fexpn(2.f * php[0]) + 1.f;
                float d1 = fexpn(2.f * php[1]) + 1.f;
                float d2 = fexpn(2.f * php[2]) + 1.f;
                float d3 = fexpn(2.f * php[3]) + 1.f;
                float iv[4]; inv4(d0, d1, d2, d3, iv);
#pragma unroll
                for (int nt = 0; nt < 4; ++nt) tnh[nt] = 1.f - 2.f * iv[nt];
            }
            float tx = 0.f, ty = 0.f, tz = 0.f;
#pragma unroll
            for (int nt = 0; nt < 4; ++nt) {
                float4 g4 = *(float4*)&sGeo[wv][16*nt + c][0];
                float tr = tnh[nt] * CRANGE * g4.w;
                tx += g4.x * tr; ty += g4.y * tr; tz += g4.z * tr;
            }
            tx += __shfl_xor(tx, 1); tx += __shfl_xor(tx, 2); tx += __shfl_xor(tx, 4); tx += __shfl_xor(tx, 8);
            ty += __shfl_xor(ty, 1); ty += __shfl_xor(ty, 2); ty += __shfl_xor(ty, 4); ty += __shfl_xor(ty, 8);
            tz += __shfl_xor(tz, 1); tz += __shfl_xor(tz, 2); tz += __shfl_xor(tz, 4); tz += __shfl_xor(tz, 8);
            if (e == 0) {
                atomicAdd(&sCoord[0], tx);
                atomicAdd(&sCoord[1], ty);
                atomicAdd(&sCoord[2], tz);
            }

            __syncthreads();
            if (t < 64) p.agg[i * 64 + t] = sAgg[t];
            if (t >= 64 && t < 67) {
                int d = t - 64;
                coordOut[i * 3 + d] = (coordIn[i * 3 + d] + sCoord[d]) * nmi;
            }
            __syncthreads();   // LDS reuse across node iterations
        }

        gridbar(p.bar + 2 * l, p.nblk);

        // ================= tail phase (skip after last layer) =================
        if (l < 3) {
            const float* trL = p.trT + l * 20480;
            const float* trN = p.trT + (l + 1) * 20480;
            const float* nw1T = trL;
            const float* nw2T = trL + 8192;
            const float* e1aT = trN + 12288;
            const float* e1bT = trN + 16384;
            const float* nb1l = p.nb1 + l * 64;
            const float* nb2l = p.nb2 + l * 64;
            const float* eb1n = p.eb1 + (l + 1) * 64;

            float* sT  = (float*)&sV[0][0];
            float* sIn = sT;            // 128
            float* sP  = sT + 128;      // 256
            float* sU  = sT + 384;      // 64
            float* sHn = sT + 448;      // 64
            float* sPB = sT + 512;      // 256
            const int cc = t & 63, pp = t >> 6;

            for (int n = blockIdx.x; n < 2048; n += gridDim.x) {
                float nmi = p.nm[n];
                if (t < 64) sIn[t] = p.h[n * 64 + t];
                else if (t < 128) sIn[t] = p.agg[n * 64 + t - 64];
                __syncthreads();
                {
                    float a = 0.f;
                    const float* w = nw1T + (pp * 32) * 64 + cc;
#pragma unroll
                    for (int k = 0; k < 32; ++k) a += w[k * 64] * sIn[pp * 32 + k];
                    sP[pp * 64 + cc] = a;
                }
                __syncthreads();
                if (t < 64) sU[t] = fsilu(sP[t] + sP[64 + t] + sP[128 + t] + sP[192 + t] + nb1l[t]);
                __syncthreads();
                {
                    float a = 0.f;
                    const float* w = nw2T + (pp * 16) * 64 + cc;
#pragma unroll
                    for (int k = 0; k < 16; ++k) a += w[k * 64] * sU[pp * 16 + k];
                    sP[pp * 64 + cc] = a;
                }
                __syncthreads();
                if (t < 64) {
                    float hn = (sIn[t] + sP[t] + sP[64 + t] + sP[128 + t] + sP[192 + t] + nb2l[t]) * nmi;
                    p.h[n * 64 + t] = hn;
                    sHn[t] = hn;
                }
                __syncthreads();
                {
                    float a = 0.f, b2 = 0.f;
                    const float* wa = e1aT + (pp * 16) * 64 + cc;
                    const float* wb = e1bT + (pp * 16) * 64 + cc;
#pragma unroll
                    for (int k = 0; k < 16; ++k) {
                        float hv = sHn[pp * 16 + k];
                        a  += wa[k * 64] * hv;
                        b2 += wb[k * 64] * hv;
                    }
                    sP[pp * 64 + cc] = a;
                    sPB[pp * 64 + cc] = b2;
                }
                __syncthreads();
                if (t < 64) {
                    p.Hr[n * 64 + t] = sP[t] + sP[64 + t] + sP[128 + t] + sP[192 + t] + eb1n[t];
                    p.Hc[n * 64 + t] = sPB[t] + sPB[64 + t] + sPB[128 + t] + sPB[192 + t];
                }
                __syncthreads();
            }
            gridbar(p.bar + 2 * l + 1, p.nblk);
        }
    }

    // ================= final: vel = cA - x0, remove masked mean (blocks 0..7) =================
    if (blockIdx.x < 8) {
        float* red = (float*)&sV[0][0];
        int b = blockIdx.x;
        int i = b * 256 + t;
        int lane = t & 63;
        float m = p.nm[i];
        float vx = (p.cA[i * 3 + 0] - p.x0[i * 3 + 0]) * m;
        float vy = (p.cA[i * 3 + 1] - p.x0[i * 3 + 1]) * m;
        float vz = (p.cA[i * 3 + 2] - p.x0[i * 3 + 2]) * m;
        if (t < 4) red[t] = 0.f;
        __syncthreads();
        float sx = vx, sy = vy, sz = vz, sn = m;
#pragma unroll
        for (int off = 1; off < 64; off <<= 1) {
            sx += __shfl_xor(sx, off);
            sy += __shfl_xor(sy, off);
            sz += __shfl_xor(sz, off);
            sn += __shfl_xor(sn, off);
        }
        if (lane == 0) {
            atomicAdd(&red[0], sx); atomicAdd(&red[1], sy);
            atomicAdd(&red[2], sz); atomicAdd(&red[3], sn);
        }
        __syncthreads();
        float invNs = frcp(red[3]);
        p.out[b * 768 + t * 3 + 0] = vx - red[0] * invNs * m;
        p.out[b * 768 + t * 3 + 1] = vy - red[1] * invNs * m;
        p.out[b * 768 + t * 3 + 2] = vz - red[2] * invNs * m;
    }
}

extern "C" void kernel_launch(void* const* d_in, const int* in_sizes, int n_in,
                              void* d_out, int out_size, void* d_ws, size_t ws_size,
                              hipStream_t stream) {
    const float* t_in    = (const float*)d_in[0];
    const float* x_in    = (const float*)d_in[1];
    const float* at_in   = (const float*)d_in[2];
    const float* aa_in   = (const float*)d_in[3];
    const float* ap_in   = (const float*)d_in[4];
    const float* nm_in   = (const float*)d_in[5];
    const float* emb_w   = (const float*)d_in[6];
    const float* emb_b   = (const float*)d_in[7];
    const float* edge_w1 = (const float*)d_in[8];
    const float* edge_b1 = (const float*)d_in[9];
    const float* edge_w2 = (const float*)d_in[10];
    const float* edge_b2 = (const float*)d_in[11];
    const float* node_w1 = (const float*)d_in[12];
    const float* node_b1 = (const float*)d_in[13];
    const float* node_w2 = (const float*)d_in[14];
    const float* node_b2 = (const float*)d_in[15];
    const float* coord_w1= (const float*)d_in[16];
    const float* coord_b1= (const float*)d_in[17];
    const float* att_w   = (const float*)d_in[18];
    const float* att_b   = (const float*)d_in[19];
    const float* coord_w2= (const float*)d_in[20];

    float* ws  = (float*)d_ws;
    float* h   = ws;                  // 131072
    float* Hr  = h + 131072;          // 131072
    float* Hc  = Hr + 131072;         // 131072
    float* agg = Hc + 131072;         // 131072
    float* x0  = agg + 131072;        // 6144
    float* cA  = x0 + 6144;           // 6144
    float* cB  = cA + 6144;           // 6144
    float* base = cB + 6144;
    half_t* wf = (half_t*)base;       // 32768 halves = 16384 float slots
    float* trT = base + 16384;        // 81920 floats
    int*   bar = (int*)(trT + 81920); // 16 ints

    float* out = (float*)d_out;

    k_prepinit<<<848, 256, 0, stream>>>(edge_w2, coord_w1, node_w1, node_w2, edge_w1,
                                        wf, trT, bar,
                                        t_in, x_in, at_in, aa_in, ap_in, nm_in,
                                        emb_w, emb_b, edge_b1,
                                        h, Hr, Hc, x0, cA);

    int maxB = 0;
    (void)hipOccupancyMaxActiveBlocksPerMultiprocessor(&maxB, k_mega, 256, 0);
    if (maxB < 1) maxB = 1;
    if (maxB > 8) maxB = 8;
    int grid = maxB * 256;            // 256 CUs on gfx950
    if (grid > 2048) grid = 2048;

    MP p;
    p.x0 = x0; p.cA = cA; p.cB = cB;
    p.Hr = Hr; p.Hc = Hc; p.h = h; p.agg = agg;
    p.ew1 = edge_w1; p.eb1 = edge_b1; p.eb2 = edge_b2; p.cb1 = coord_b1;
    p.attw = att_w; p.attb = att_b; p.cw2 = coord_w2; p.nm = nm_in;
    p.wf = wf; p.trT = trT;
    p.nb1 = node_b1; p.nb2 = node_b2;
    p.out = out; p.bar = bar; p.nblk = grid;

    k_mega<<<grid, 256, 0, stream>>>(p);
}